// Round 15
// baseline (287.677 us; speedup 1.0000x reference)
//
#include <hip/hip_runtime.h>

#define BN 40000
#define TT 12
#define EE 160000

typedef __attribute__((ext_vector_type(4))) float f32x4;
typedef __attribute__((ext_vector_type(4))) short s16x4;
typedef __attribute__((ext_vector_type(8))) short s16x8;

__device__ __forceinline__ float lrelu(float v){ return v > 0.f ? v : 0.2f*v; }

__device__ __forceinline__ short bf(float f){
  union { float f; unsigned u; } x; x.f = f;
  unsigned r = x.u + 0x7fffu + ((x.u >> 16) & 1u);
  return (short)(r >> 16);
}

// packed RNE f32->bf16 pair (lo in [15:0], hi in [31:16])
__device__ __forceinline__ unsigned cvtpk(float lo, float hi){
  unsigned r;
  asm("v_cvt_pk_bf16_f32 %0, %1, %2" : "=v"(r) : "v"(lo), "v"(hi));
  return r;
}

// ---------------- merged hist + prep ----------------
// wp layout (row-major canonical):
//   QKV1 0      [j][72]       13824
//   BC1  13824  [dt*64+o][72] 13824
//   FC1  27648  [dt*64+o][72] 13824
//   OUT1 41472  [o][72]        4608
//   GWTC 46080  [o][40]        2560
__global__ void k_histprep(const int* __restrict__ ei, int* __restrict__ degcnt, int* __restrict__ cnt,
                       const float* __restrict__ cheb_w, const float* __restrict__ cheb_b,
                       const float* __restrict__ gat_w, const float* __restrict__ att_src,
                       const float* __restrict__ att_dst, const float* __restrict__ gat_b,
                       const float* __restrict__ tc_w, const float* __restrict__ tc_b,
                       const float* __restrict__ in_w, const float* __restrict__ out_w,
                       const float* __restrict__ bc_w, const float* __restrict__ fc_w,
                       float* __restrict__ gwbuf, short* __restrict__ wp, float* __restrict__ btcT){
  if (blockIdx.x < 625){
    int e = blockIdx.x*256 + threadIdx.x;
    if (e < EE){
      atomicAdd(&degcnt[ei[e]], 1);
      atomicAdd(&cnt[ei[EE + e]], 1);
    }
    return;
  }
  if (blockIdx.x == 625){
    __shared__ float sgw[384]; __shared__ float sgc[128];
    int hc = threadIdx.x;
    if (hc < 128){
      for (int k=0;k<3;++k){
        float a=0; for (int c=0;c<64;++c) a += cheb_w[k*64+c]*gat_w[hc*64+c];
        sgw[k*128+hc]=a; gwbuf[k*128+hc]=a;
      }
      float g=0; for (int c=0;c<64;++c) g += cheb_b[c]*gat_w[hc*64+c];
      sgc[hc]=g; gwbuf[384+hc]=g;
    }
    __syncthreads();
    if (hc<6){ int k=hc>>1, h=hc&1; float a=0,d=0;
      for (int c=0;c<64;++c){ float g=sgw[k*128+h*64+c]; a+=g*att_src[h*64+c]; d+=g*att_dst[h*64+c]; }
      gwbuf[512+hc]=a; gwbuf[518+hc]=d; }
    if (hc<2){ float a=0,d=0;
      for (int c=0;c<64;++c){ float g=sgc[hc*64+c]; a+=g*att_src[hc*64+c]; d+=g*att_dst[hc*64+c]; }
      gwbuf[524+hc]=a; gwbuf[526+hc]=d; }
    __syncthreads();
    if (hc < 64){
      int o = hc;
      short* gw2 = wp + 46080;
      float sbias[3];
      for (int dt=0; dt<3; ++dt){
        float s[6] = {0,0,0,0,0,0};
        float sb = 0.f;
        for (int c=0;c<64;++c){
          float wv = tc_w[o*192 + c*3 + dt];
          for (int j=0;j<3;++j){
            s[j]   += wv * sgw[j*128 + c];
            s[3+j] += wv * sgw[j*128 + 64 + c];
          }
          sb += wv * (gat_b[c] + 0.5f*(sgc[c] + sgc[64+c]));
        }
        for (int j=0;j<6;++j) gw2[o*40 + dt*6 + j] = bf(s[j]);
        sbias[dt] = sb;
      }
      for (int k=18;k<40;++k) gw2[o*40+k] = 0;
      for (int t=0;t<16;++t){
        float b = tc_b[o];
        if (t < 12){
          if (t > 0)  b += sbias[0];
          b += sbias[1];
          if (t < 11) b += sbias[2];
        }
        btcT[o*16+t] = b;   // transposed: [o][t] so consumer does float4 over t
      }
    }
    return;
  }
  int i = (blockIdx.x-626)*256 + threadIdx.x;
  if (i >= 46080) return;
  float v;
  if (i < 13824){ int j=i/72, k=i%72; v = (k<64)? in_w[j*64+k] : 0.f; }
  else if (i < 27648){ int d=i-13824; int dt=d/4608, rr=d%4608, o=rr/72, c=rr%72; v = (c<64)? bc_w[o*192+c*3+dt] : 0.f; }
  else if (i < 41472){ int d=i-27648; int dt=d/4608, rr=d%4608, o=rr/72, c=rr%72; v = (c<64)? fc_w[o*192+c*3+dt] : 0.f; }
  else               { int d=i-41472; int o=d/72, c=d%72; v = (c<64)? out_w[o*64+c] : 0.f; }
  wp[i] = bf(v);
}

// ---------------- scan phase A (blocks<157) + repack (blocks>=157) ----------------
// repack: wp2 frag ids f2: QKV 0..23 (grp*8+nt*2+kc) | OUT 24..31 | BC 32..55 | FC 56..79
__global__ void k_scanA(const int* __restrict__ cnt, int* __restrict__ bsum,
                        const short* __restrict__ wp, short* __restrict__ wp2){
  if (blockIdx.x >= 157){
    int i = (blockIdx.x-157)*256 + threadIdx.x;
    if (i >= 40960) return;
    int f2 = i >> 9, lane = (i >> 3) & 63, e = i & 7;
    int l15 = lane & 15, l4 = lane >> 4;
    int src;
    if (f2 < 24){
      int grp = f2 >> 3, nt = (f2 >> 1) & 3, kc = f2 & 1;
      src = 0     + ((grp*4+nt)*16 + l15)*72 + kc*32 + l4*8 + e;
    } else if (f2 < 32){
      int g = f2 - 24; int mt = g >> 1, kc = g & 1;
      src = 41472 + (mt*16 + l15)*72 + kc*32 + l4*8 + e;
    } else if (f2 < 56){
      int g = f2 - 32; int dt = g >> 3, kc = (g >> 2) & 1, nt = g & 3;
      src = 13824 + (dt*64 + nt*16 + l15)*72 + kc*32 + l4*8 + e;
    } else {
      int g = f2 - 56; int dt = g >> 3, kc = (g >> 2) & 1, nt = g & 3;
      src = 27648 + (dt*64 + nt*16 + l15)*72 + kc*32 + l4*8 + e;
    }
    wp2[i] = wp[src];
    return;
  }
  __shared__ int s[256];
  int i = blockIdx.x*256 + threadIdx.x;
  int v = (i < BN) ? cnt[i] : 0;
  s[threadIdx.x] = v; __syncthreads();
  for (int off=128; off>0; off>>=1){
    if (threadIdx.x < off) s[threadIdx.x] += s[threadIdx.x+off];
    __syncthreads();
  }
  if (threadIdx.x == 0) bsum[blockIdx.x] = s[0];
}

__global__ void k_scanB(const int* __restrict__ bsum, int* __restrict__ bbase, int* __restrict__ rowptr){
  __shared__ int s[256];
  int tid = threadIdx.x;
  int v = (tid < 157) ? bsum[tid] : 0;
  s[tid] = v; __syncthreads();
  for (int off=1; off<256; off<<=1){
    int t = (tid>=off) ? s[tid-off] : 0;
    __syncthreads();
    s[tid] += t;
    __syncthreads();
  }
  if (tid < 157) bbase[tid] = s[tid] - v;   // exclusive
  if (tid == 0) rowptr[BN] = EE;
}

__global__ void k_scanC(const int* __restrict__ cnt, const int* __restrict__ bbase,
                        int* __restrict__ rowptr, int* __restrict__ cursor){
  __shared__ int s[256];
  int i = blockIdx.x*256 + threadIdx.x;
  int v = (i < BN) ? cnt[i] : 0;
  s[threadIdx.x] = v; __syncthreads();
  for (int off=1; off<256; off<<=1){
    int t = (threadIdx.x>=off) ? s[threadIdx.x-off] : 0;
    __syncthreads();
    s[threadIdx.x] += t;
    __syncthreads();
  }
  if (i < BN){
    int r = bbase[blockIdx.x] + s[threadIdx.x] - v;
    rowptr[i] = r; cursor[i] = r;
  }
}

__global__ void k_scatter(const int* __restrict__ ei, const int* __restrict__ degcnt,
                          int* __restrict__ cursor, int* __restrict__ esrc, float* __restrict__ ew){
  int e = blockIdx.x*256 + threadIdx.x;
  if (e < EE){
    int s = ei[e], d = ei[EE+e];
    int p = atomicAdd(&cursor[d], 1);
    esrc[p] = s;
    int ds_ = degcnt[s], dd_ = degcnt[d];
    float isd = ds_ > 0 ? rsqrtf((float)ds_) : 0.f;
    float idd = dd_ > 0 ? rsqrtf((float)dd_) : 0.f;
    ew[p] = -isd*idd;
  }
}

// ---------------- Cheb propagation ----------------
__global__ void k_prop1v(const float* __restrict__ x, const int* __restrict__ rowptr,
                         const int* __restrict__ esrc, const float* __restrict__ ew,
                         float* __restrict__ tx1){
  int i = blockIdx.x*256 + threadIdx.x;
  if (i >= BN*3) return;
  int d = i/3, q = i - d*3;
  int r0 = rowptr[d], r1 = rowptr[d+1];
  float4 a = {0.f,0.f,0.f,0.f};
  for (int p=r0;p<r1;++p){
    float wv = ew[p];
    float4 v = ((const float4*)x)[esrc[p]*3 + q];
    a.x += wv*v.x; a.y += wv*v.y; a.z += wv*v.z; a.w += wv*v.w;
  }
  ((float4*)tx1)[i] = a;
}

__global__ void k_prop2v(const float* __restrict__ x, const float* __restrict__ tx1,
                         const int* __restrict__ rowptr, const int* __restrict__ esrc,
                         const float* __restrict__ ew, float* __restrict__ tx2){
  int i = blockIdx.x*256 + threadIdx.x;
  if (i >= BN*3) return;
  int d = i/3, q = i - d*3;
  int r0 = rowptr[d], r1 = rowptr[d+1];
  float4 a = {0.f,0.f,0.f,0.f};
  for (int p=r0;p<r1;++p){
    float wv = ew[p];
    float4 v = ((const float4*)tx1)[esrc[p]*3 + q];
    a.x += wv*v.x; a.y += wv*v.y; a.z += wv*v.z; a.w += wv*v.w;
  }
  float4 xv = ((const float4*)x)[i];
  float4 o; o.x = 2.f*a.x - xv.x; o.y = 2.f*a.y - xv.y; o.z = 2.f*a.z - xv.z; o.w = 2.f*a.w - xv.w;
  ((float4*)tx2)[i] = o;
}

// ---------------- GAT: thread = (node, t-quarter), BOTH heads ----------------
__global__ __launch_bounds__(256) void k_gat4(const float* __restrict__ x, const float* __restrict__ tx1,
     const float* __restrict__ tx2, const int* __restrict__ rowptr, const int* __restrict__ esrc,
     const float* __restrict__ gwbuf, float* __restrict__ coef, int cst){
  int i = blockIdx.x*256 + threadIdx.x;
  if (i >= BN*3) return;
  int d = i/3, q = i - d*3;

  float as[2][3], ad[2][3], asc[2], adc[2];
  #pragma unroll
  for (int h=0;h<2;++h){
    #pragma unroll
    for (int k=0;k<3;++k){ as[h][k] = gwbuf[512+2*k+h]; ad[h][k] = gwbuf[518+2*k+h]; }
    asc[h] = gwbuf[524+h]; adc[h] = gwbuf[526+h];
  }

  float4 t0 = ((const float4*)x)[d*3+q];
  float4 t1 = ((const float4*)tx1)[d*3+q];
  float4 t2 = ((const float4*)tx2)[d*3+q];
  float td0[4] = {t0.x,t0.y,t0.z,t0.w};
  float td1[4] = {t1.x,t1.y,t1.z,t1.w};
  float td2[4] = {t2.x,t2.y,t2.z,t2.w};

  float adh[2][4], S0[2][4], S1[2][4], S2[2][4], Z[2][4];
  #pragma unroll
  for (int h=0;h<2;++h){
    #pragma unroll
    for (int t=0;t<4;++t){
      adh[h][t] = td0[t]*ad[h][0] + td1[t]*ad[h][1] + td2[t]*ad[h][2] + adc[h];
      float es = lrelu(td0[t]*as[h][0] + td1[t]*as[h][1] + td2[t]*as[h][2] + asc[h] + adh[h][t]);
      float p = __expf(es);
      S0[h][t] = p*td0[t]; S1[h][t] = p*td1[t]; S2[h][t] = p*td2[t]; Z[h][t] = p;
    }
  }
  int r0 = rowptr[d], r1 = rowptr[d+1];
  for (int p=r0;p<r1;++p){
    int s = esrc[p];
    float4 v0 = ((const float4*)x)[s*3+q];
    float4 v1 = ((const float4*)tx1)[s*3+q];
    float4 v2 = ((const float4*)tx2)[s*3+q];
    float s0[4] = {v0.x,v0.y,v0.z,v0.w};
    float s1[4] = {v1.x,v1.y,v1.z,v1.w};
    float s2[4] = {v2.x,v2.y,v2.z,v2.w};
    #pragma unroll
    for (int h=0;h<2;++h){
      #pragma unroll
      for (int t=0;t<4;++t){
        float e = lrelu(s0[t]*as[h][0] + s1[t]*as[h][1] + s2[t]*as[h][2] + asc[h] + adh[h][t]);
        float pp = __expf(e);
        S0[h][t] += pp*s0[t]; S1[h][t] += pp*s1[t]; S2[h][t] += pp*s2[t]; Z[h][t] += pp;
      }
    }
  }
  float* cw = coef + (size_t)d*cst + q*32;
  #pragma unroll
  for (int t=0;t<4;++t){
    float inv0 = 0.5f/Z[0][t], inv1 = 0.5f/Z[1][t];
    float4 w4; w4.x = S0[0][t]*inv0; w4.y = S1[0][t]*inv0; w4.z = S2[0][t]*inv0; w4.w = S0[1][t]*inv1;
    *(float4*)(cw + t*8) = w4;
    float2 w2; w2.x = S1[1][t]*inv1; w2.y = S2[1][t]*inv1;
    *(float2*)(cw + t*8 + 4) = w2;
  }
}

// ---------------- fused temporal: 7 waves x 2 nodes / 448-thread block, 53.8 KB LDS, NO barrier ----------------
// per node (3840 shorts): +0 tcO->Q->O [16][72] | +1152 K[16][72] -> R[18][72]
//   +2304 Vt[64][16] | +3328 Pb[16][16] | +3584 Pb2[16][16]
// identical math to R12 k_temporal9; each wave processes TWO nodes (unrolled) for cross-node ILP
__global__ __launch_bounds__(448) void k_temporal9b(
  const float* __restrict__ coef, int cst, const float* __restrict__ x,
  const short* __restrict__ wp, const short* __restrict__ wp2, const float* __restrict__ btcT,
  const float* __restrict__ in_b, const float* __restrict__ out_b,
  const float* __restrict__ res_w, const float* __restrict__ res_b,
  const float* __restrict__ ln_g, const float* __restrict__ ln_b,
  const float* __restrict__ bc_b, const float* __restrict__ fc_b,
  float* __restrict__ out)
{
  __shared__ __align__(16) short lds[26880];   // 7 * 3840 = 53.8 KiB

  const int tid = threadIdx.x;
  const int wv = tid >> 6;
  const int lane = tid & 63;
  const int l15 = lane & 15, l4 = lane >> 4;

  short* nb  = lds + wv*3840;
  short* tcO = nb;            // tc out -> Q -> O
  short* K   = nb + 1152;
  short* R   = nb + 1152;     // [18][72] over K + head of Vt (both dead after P3)
  short* Vt  = nb + 2304;     // [64][16]
  short* Pb  = nb + 3328;     // [16][16]
  short* Pb2 = nb + 3584;     // [16][16]

  const f32x4 z4 = {0.f,0.f,0.f,0.f};
  s16x8 zf;
  #pragma unroll
  for (int j=0;j<8;++j) zf[j]=0;

  #pragma unroll
  for (int it=0; it<2; ++it){
    const int nd = blockIdx.x*14 + wv*2 + it;
    if (nd >= BN) continue;

    // ---- A-fragment in registers: A[t=l15][k=l4*8+e], k=dt*6+j, zeros k>=18
    s16x8 aA;
    {
      const float* cb = coef + (size_t)nd*cst;
      float av[8];
      #pragma unroll
      for (int e=0; e<8; ++e){
        int k = l4*8 + e;
        float v = 0.f;
        if (k < 18){
          int dt = (k>=12) ? 2 : ((k>=6) ? 1 : 0);
          int j = k - dt*6;
          int u = l15 - 1 + dt;
          if (u >= 0 && u < 12) v = cb[u*8 + j];
        }
        av[e] = v;
      }
      unsigned* ap = (unsigned*)&aA;
      ap[0]=cvtpk(av[0],av[1]); ap[1]=cvtpk(av[2],av[3]);
      ap[2]=cvtpk(av[4],av[5]); ap[3]=cvtpk(av[6],av[7]);
    }

    // ---- P1: tc GEMM (A = coef regs, B = gwtc global row-major) -> tcO[t][o]
    {
      #pragma unroll
      for (int nt=0; nt<4; ++nt){
        s16x8 b = *(const s16x8*)&wp[46080 + (nt*16+l15)*40 + l4*8];
        f32x4 acc = __builtin_amdgcn_mfma_f32_16x16x32_bf16(aA, b, z4, 0,0,0);  // row=t, col=o
        float4 bb = *(const float4*)&btcT[(nt*16+l15)*16 + l4*4];
        unsigned p01 = cvtpk(acc[0]+bb.x, acc[1]+bb.y);
        unsigned p23 = cvtpk(acc[2]+bb.z, acc[3]+bb.w);
        int c = nt*16 + l15, rb = l4*4;
        tcO[(rb+0)*72+c] = (short)p01; tcO[(rb+1)*72+c] = (short)(p01>>16);
        tcO[(rb+2)*72+c] = (short)p23; tcO[(rb+3)*72+c] = (short)(p23>>16);
      }
    }

    // ---- P2: QKV GEMM (B-frags from global wp2) -> Q(=tcO region), K, Vt
    {
      s16x8 a0 = *(const s16x8*)&tcO[l15*72 +  0 + l4*8];
      s16x8 a1 = *(const s16x8*)&tcO[l15*72 + 32 + l4*8];
      #pragma unroll
      for (int grp=0; grp<3; ++grp){
        f32x4 acc[4];
        #pragma unroll
        for (int nt=0; nt<4; ++nt){
          s16x8 b0 = *(const s16x8*)&wp2[(((grp*8 + nt*2 + 0)*64 + lane))*8];
          acc[nt] = __builtin_amdgcn_mfma_f32_16x16x32_bf16(a0, b0, z4, 0,0,0);
          s16x8 b1 = *(const s16x8*)&wp2[(((grp*8 + nt*2 + 1)*64 + lane))*8];
          acc[nt] = __builtin_amdgcn_mfma_f32_16x16x32_bf16(a1, b1, acc[nt], 0,0,0);
        }
        #pragma unroll
        for (int nt=0; nt<4; ++nt){
          float bb = in_b[(grp*4+nt)*16 + l15];
          unsigned p01 = cvtpk(acc[nt][0]+bb, acc[nt][1]+bb);
          unsigned p23 = cvtpk(acc[nt][2]+bb, acc[nt][3]+bb);
          if (grp==0){
            int c = nt*16+l15, rb = l4*4;
            tcO[(rb+0)*72+c] = (short)p01; tcO[(rb+1)*72+c] = (short)(p01>>16);
            tcO[(rb+2)*72+c] = (short)p23; tcO[(rb+3)*72+c] = (short)(p23>>16);
          } else if (grp==1){
            int c = nt*16+l15, rb = l4*4;
            K[(rb+0)*72+c] = (short)p01; K[(rb+1)*72+c] = (short)(p01>>16);
            K[(rb+2)*72+c] = (short)p23; K[(rb+3)*72+c] = (short)(p23>>16);
          } else {
            int2 pk2; pk2.x = (int)p01; pk2.y = (int)p23;
            *(int2*)&Vt[(nt*16 + l15)*16 + l4*4] = pk2;
          }
        }
      }
    }

    // ---- P3: attention, heads in PAIRS (dual P buffers -> two independent chains in flight)
    {
      #pragma unroll 1
      for (int hp=0; hp<2; ++hp){
        const int h0 = hp*2, h1 = hp*2 + 1;
        s16x8 qa0 = zf, kb0 = zf, qa1 = zf, kb1 = zf;
        if (l4 < 2){
          qa0 = *(const s16x8*)&tcO[l15*72 + h0*16 + l4*8];   // Q h0
          kb0 = *(const s16x8*)&K[l15*72 + h0*16 + l4*8];
          qa1 = *(const s16x8*)&tcO[l15*72 + h1*16 + l4*8];   // Q h1
          kb1 = *(const s16x8*)&K[l15*72 + h1*16 + l4*8];
        }
        f32x4 sc0 = __builtin_amdgcn_mfma_f32_16x16x32_bf16(qa0, kb0, z4, 0,0,0);  // row=q, col=kt
        f32x4 sc1 = __builtin_amdgcn_mfma_f32_16x16x32_bf16(qa1, kb1, z4, 0,0,0);
        float invz0[4], invz1[4], ev0[4], ev1[4];
        #pragma unroll
        for (int r=0; r<4; ++r){
          float e0 = (l15 < 12) ? __expf(sc0[r]*0.25f) : 0.f;
          float e1 = (l15 < 12) ? __expf(sc1[r]*0.25f) : 0.f;
          float z0 = e0, z1 = e1;
          #pragma unroll
          for (int dd=1; dd<16; dd<<=1){ z0 += __shfl_xor(z0, dd); z1 += __shfl_xor(z1, dd); }
          invz0[r] = 1.f/z0; invz1[r] = 1.f/z1;
          ev0[r] = e0; ev1[r] = e1;
        }
        {
          unsigned a01 = cvtpk(ev0[0],ev0[1]), a23 = cvtpk(ev0[2],ev0[3]);
          unsigned b01 = cvtpk(ev1[0],ev1[1]), b23 = cvtpk(ev1[2],ev1[3]);
          int rb = l4*4, c = l15;
          Pb [(rb+0)*16+c] = (short)a01; Pb [(rb+1)*16+c] = (short)(a01>>16);
          Pb [(rb+2)*16+c] = (short)a23; Pb [(rb+3)*16+c] = (short)(a23>>16);
          Pb2[(rb+0)*16+c] = (short)b01; Pb2[(rb+1)*16+c] = (short)(b01>>16);
          Pb2[(rb+2)*16+c] = (short)b23; Pb2[(rb+3)*16+c] = (short)(b23>>16);
        }
        s16x8 pa0 = zf, vb0 = zf, pa1 = zf, vb1 = zf;
        if (l4 < 2){
          pa0 = *(const s16x8*)&Pb [l15*16 + l4*8];
          vb0 = *(const s16x8*)&Vt[(h0*16 + l15)*16 + l4*8];
          pa1 = *(const s16x8*)&Pb2[l15*16 + l4*8];
          vb1 = *(const s16x8*)&Vt[(h1*16 + l15)*16 + l4*8];
        }
        f32x4 ov0 = __builtin_amdgcn_mfma_f32_16x16x32_bf16(pa0, vb0, z4, 0,0,0);  // row=q, col=dh
        f32x4 ov1 = __builtin_amdgcn_mfma_f32_16x16x32_bf16(pa1, vb1, z4, 0,0,0);
        {
          unsigned a01 = cvtpk(ov0[0]*invz0[0], ov0[1]*invz0[1]);
          unsigned a23 = cvtpk(ov0[2]*invz0[2], ov0[3]*invz0[3]);
          unsigned b01 = cvtpk(ov1[0]*invz1[0], ov1[1]*invz1[1]);
          unsigned b23 = cvtpk(ov1[2]*invz1[2], ov1[3]*invz1[3]);
          int c0 = h0*16 + l15, c1 = h1*16 + l15, rb = l4*4;
          tcO[(rb+0)*72+c0] = (short)a01; tcO[(rb+1)*72+c0] = (short)(a01>>16);
          tcO[(rb+2)*72+c0] = (short)a23; tcO[(rb+3)*72+c0] = (short)(a23>>16);
          tcO[(rb+0)*72+c1] = (short)b01; tcO[(rb+1)*72+c1] = (short)(b01>>16);
          tcO[(rb+2)*72+c1] = (short)b23; tcO[(rb+3)*72+c1] = (short)(b23>>16);
        }
      }
    }

    // ---- P4: out-proj (frags from global wp2) + residual + relu + LN -> R[u][o]
    {
      s16x4 zz; zz[0]=0; zz[1]=0; zz[2]=0; zz[3]=0;
      for (int i=lane; i<108; i+=64){
        int rr = i/18, cc = i%18;
        int row = (rr==0) ? 0 : (12 + rr);
        *(s16x4*)&R[row*72 + cc*4] = zz;
      }
      s16x8 a0 = *(const s16x8*)&tcO[l15*72 +  0 + l4*8];
      s16x8 a1 = *(const s16x8*)&tcO[l15*72 + 32 + l4*8];
      f32x4 acc[4];
      #pragma unroll
      for (int nt=0; nt<4; ++nt){
        s16x8 w0 = *(const s16x8*)&wp2[(((24 + nt*2 + 0)*64 + lane))*8];
        acc[nt] = __builtin_amdgcn_mfma_f32_16x16x32_bf16(a0, w0, z4, 0,0,0);
        s16x8 w1 = *(const s16x8*)&wp2[(((24 + nt*2 + 1)*64 + lane))*8];
        acc[nt] = __builtin_amdgcn_mfma_f32_16x16x32_bf16(a1, w1, acc[nt], 0,0,0); // row=t, col=o
      }
      float4 xv = {0.f,0.f,0.f,0.f};
      if (l4 < 3) xv = *(const float4*)&x[(size_t)nd*12 + l4*4];
      float xr[4] = {xv.x, xv.y, xv.z, xv.w};
      float zr[4][4], sum[4]={0,0,0,0}, sq[4]={0,0,0,0};
      #pragma unroll
      for (int nt=0; nt<4; ++nt){
        int o = nt*16 + l15;
        float ob=out_b[o], rw=res_w[o], rb2=res_b[o];
        #pragma unroll
        for (int r=0; r<4; ++r){
          float v = acc[nt][r] + ob + xr[r]*rw + rb2;
          v = v>0.f ? v : 0.f;
          zr[nt][r]=v; sum[r]+=v; sq[r]+=v*v;
        }
      }
      #pragma unroll
      for (int r=0; r<4; ++r){
        #pragma unroll
        for (int dd=1; dd<16; dd<<=1){ sum[r]+=__shfl_xor(sum[r],dd); sq[r]+=__shfl_xor(sq[r],dd); }
      }
      if (l4 < 3){
        float mu4[4], iv4[4];
        #pragma unroll
        for (int r=0; r<4; ++r){
          float mu = sum[r]*(1.f/64.f);
          float va = sq[r]*(1.f/64.f) - mu*mu;
          mu4[r] = mu; iv4[r] = rsqrtf(fmaxf(va,0.f) + 1e-5f);
        }
        #pragma unroll
        for (int nt=0; nt<4; ++nt){
          int o = nt*16 + l15;
          float g = ln_g[o], b2 = ln_b[o];
          float r0 = (zr[nt][0]-mu4[0])*iv4[0]*g + b2;
          float r1 = (zr[nt][1]-mu4[1])*iv4[1]*g + b2;
          float r2 = (zr[nt][2]-mu4[2])*iv4[2]*g + b2;
          float r3 = (zr[nt][3]-mu4[3])*iv4[3]*g + b2;
          unsigned p01 = cvtpk(r0,r1), p23 = cvtpk(r2,r3);
          int rb = l4*4;
          R[(rb+1)*72+o] = (short)p01; R[(rb+2)*72+o] = (short)(p01>>16);
          R[(rb+3)*72+o] = (short)p23; R[(rb+4)*72+o] = (short)(p23>>16);
        }
      }
    }

    // ---- P5+P6 fused: backcast+forecast convs (A = R rows, B = global wp2 frags)
    {
      f32x4 aB[4] = {z4,z4,z4,z4};
      f32x4 aF[4] = {z4,z4,z4,z4};
      #pragma unroll
      for (int dt=0; dt<3; ++dt){
        #pragma unroll
        for (int kc=0; kc<2; ++kc){
          s16x8 ar = *(const s16x8*)&R[(l15 + dt)*72 + kc*32 + l4*8];
          #pragma unroll
          for (int nt=0; nt<4; ++nt){
            s16x8 wb = *(const s16x8*)&wp2[16384 + (((dt*8 + kc*4 + nt)*64 + lane))*8];
            aB[nt] = __builtin_amdgcn_mfma_f32_16x16x32_bf16(ar, wb, aB[nt], 0,0,0);
            s16x8 wf = *(const s16x8*)&wp2[28672 + (((dt*8 + kc*4 + nt)*64 + lane))*8];
            aF[nt] = __builtin_amdgcn_mfma_f32_16x16x32_bf16(ar, wf, aF[nt], 0,0,0);
          }
        }
      }
      if (l4 < 3){
        #pragma unroll
        for (int nt=0; nt<4; ++nt){
          int o = nt*16 + l15;
          float bb = bc_b[o], fb = fc_b[o];
          float4 v; v.x=aB[nt][0]+bb; v.y=aB[nt][1]+bb; v.z=aB[nt][2]+bb; v.w=aB[nt][3]+bb;
          *(float4*)&out[(size_t)nd*768 + o*12 + l4*4] = v;
          float4 f; f.x=aF[nt][0]+fb; f.y=aF[nt][1]+fb; f.z=aF[nt][2]+fb; f.w=aF[nt][3]+fb;
          *(float4*)&out[30720000 + (size_t)nd*768 + o*12 + l4*4] = f;
        }
      }
    }
  }
}

// ---------------- host ----------------
extern "C" void kernel_launch(void* const* d_in, const int* in_sizes, int n_in,
                              void* d_out, int out_size, void* d_ws, size_t ws_size,
                              hipStream_t stream){
  const float* x      = (const float*)d_in[0];
  const int*   ei     = (const int*)d_in[1];
  const float* cheb_w = (const float*)d_in[2];
  const float* cheb_b = (const float*)d_in[3];
  const float* gat_w  = (const float*)d_in[4];
  const float* att_src= (const float*)d_in[5];
  const float* att_dst= (const float*)d_in[6];
  const float* gat_b  = (const float*)d_in[7];
  const float* tc_w   = (const float*)d_in[8];
  const float* tc_b   = (const float*)d_in[9];
  const float* in_w   = (const float*)d_in[10];
  const float* in_b   = (const float*)d_in[11];
  const float* out_w  = (const float*)d_in[12];
  const float* out_b  = (const float*)d_in[13];
  const float* res_w  = (const float*)d_in[14];
  const float* res_b  = (const float*)d_in[15];
  const float* ln_g   = (const float*)d_in[16];
  const float* ln_b   = (const float*)d_in[17];
  const float* bc_w   = (const float*)d_in[18];
  const float* bc_b   = (const float*)d_in[19];
  const float* fc_w   = (const float*)d_in[20];
  const float* fc_b   = (const float*)d_in[21];
  float* out = (float*)d_out;

  char* w = (char*)d_ws;
  size_t off = 0;
  auto alloc = [&](size_t bytes)->void*{ void* p = w + off; off += (bytes + 255) & ~(size_t)255; return p; };
  int*   cnt2   = (int*)alloc((size_t)2*BN*4);
  int*   degcnt = cnt2;
  int*   cnt    = cnt2 + BN;
  int*   rowptr = (int*)alloc((size_t)(BN+1)*4);
  int*   cursor = (int*)alloc((size_t)BN*4);
  int*   esrc   = (int*)alloc((size_t)EE*4);
  float* ew     = (float*)alloc((size_t)EE*4);
  float* tx1    = (float*)alloc((size_t)BN*TT*4);
  float* tx2    = (float*)alloc((size_t)BN*TT*4);
  float* gwb    = (float*)alloc(1024*4);
  short* wpack  = (short*)alloc((size_t)48640*2);
  short* wpack2 = (short*)alloc((size_t)40960*2);
  float* btcT   = (float*)alloc(1024*4);
  int*   bsum   = (int*)alloc(157*4);
  int*   bbase  = (int*)alloc(157*4);

  size_t coefBytes = (size_t)BN*TT*8*4;
  float* coefp; int cst;
  if (off + coefBytes <= ws_size){ coefp = (float*)(w + off); off += coefBytes; cst = 96; }
  else { coefp = out; cst = 768; }

  hipMemsetAsync(cnt2, 0, (size_t)2*BN*4, stream);
  k_histprep<<<806, 256, 0, stream>>>(ei, degcnt, cnt, cheb_w, cheb_b, gat_w, att_src, att_dst,
                                      gat_b, tc_w, tc_b, in_w, out_w, bc_w, fc_w, gwb, wpack, btcT);
  k_scanA   <<<317, 256, 0, stream>>>(cnt, bsum, wpack, wpack2);
  k_scanB   <<<1, 256, 0, stream>>>(bsum, bbase, rowptr);
  k_scanC   <<<157, 256, 0, stream>>>(cnt, bbase, rowptr, cursor);
  k_scatter <<<(EE+255)/256, 256, 0, stream>>>(ei, degcnt, cursor, esrc, ew);
  k_prop1v  <<<(BN*3+255)/256, 256, 0, stream>>>(x, rowptr, esrc, ew, tx1);
  k_prop2v  <<<(BN*3+255)/256, 256, 0, stream>>>(x, tx1, rowptr, esrc, ew, tx2);
  k_gat4    <<<(BN*3+255)/256, 256, 0, stream>>>(x, tx1, tx2, rowptr, esrc, gwb, coefp, cst);
  k_temporal9b<<<(BN+13)/14, 448, 0, stream>>>(coefp, cst, x, wpack, wpack2, btcT, in_b, out_b,
                                               res_w, res_b, ln_g, ln_b, bc_b, fc_b, out);
}

// Round 16
// 264.229 us; speedup vs baseline: 1.0887x; 1.0887x over previous
//
#include <hip/hip_runtime.h>

#define BN 40000
#define TT 12
#define EE 160000

typedef __attribute__((ext_vector_type(4))) float f32x4;
typedef __attribute__((ext_vector_type(4))) short s16x4;
typedef __attribute__((ext_vector_type(8))) short s16x8;

__device__ __forceinline__ float lrelu(float v){ return v > 0.f ? v : 0.2f*v; }

__device__ __forceinline__ short bf(float f){
  union { float f; unsigned u; } x; x.f = f;
  unsigned r = x.u + 0x7fffu + ((x.u >> 16) & 1u);
  return (short)(r >> 16);
}

// packed RNE f32->bf16 pair (lo in [15:0], hi in [31:16])
__device__ __forceinline__ unsigned cvtpk(float lo, float hi){
  unsigned r;
  asm("v_cvt_pk_bf16_f32 %0, %1, %2" : "=v"(r) : "v"(lo), "v"(hi));
  return r;
}

// ---------------- merged hist + prep ----------------
// wp layout (row-major canonical):
//   QKV1 0      [j][72]       13824
//   BC1  13824  [dt*64+o][72] 13824
//   FC1  27648  [dt*64+o][72] 13824
//   OUT1 41472  [o][72]        4608
//   GWTC 46080  [o][40]        2560
__global__ void k_histprep(const int* __restrict__ ei, int* __restrict__ degcnt, int* __restrict__ cnt,
                       const float* __restrict__ cheb_w, const float* __restrict__ cheb_b,
                       const float* __restrict__ gat_w, const float* __restrict__ att_src,
                       const float* __restrict__ att_dst, const float* __restrict__ gat_b,
                       const float* __restrict__ tc_w, const float* __restrict__ tc_b,
                       const float* __restrict__ in_w, const float* __restrict__ out_w,
                       const float* __restrict__ bc_w, const float* __restrict__ fc_w,
                       float* __restrict__ gwbuf, short* __restrict__ wp, float* __restrict__ btcT){
  if (blockIdx.x < 625){
    int e = blockIdx.x*256 + threadIdx.x;
    if (e < EE){
      atomicAdd(&degcnt[ei[e]], 1);
      atomicAdd(&cnt[ei[EE + e]], 1);
    }
    return;
  }
  if (blockIdx.x == 625){
    __shared__ float sgw[384]; __shared__ float sgc[128];
    int hc = threadIdx.x;
    if (hc < 128){
      for (int k=0;k<3;++k){
        float a=0; for (int c=0;c<64;++c) a += cheb_w[k*64+c]*gat_w[hc*64+c];
        sgw[k*128+hc]=a; gwbuf[k*128+hc]=a;
      }
      float g=0; for (int c=0;c<64;++c) g += cheb_b[c]*gat_w[hc*64+c];
      sgc[hc]=g; gwbuf[384+hc]=g;
    }
    __syncthreads();
    if (hc<6){ int k=hc>>1, h=hc&1; float a=0,d=0;
      for (int c=0;c<64;++c){ float g=sgw[k*128+h*64+c]; a+=g*att_src[h*64+c]; d+=g*att_dst[h*64+c]; }
      gwbuf[512+hc]=a; gwbuf[518+hc]=d; }
    if (hc<2){ float a=0,d=0;
      for (int c=0;c<64;++c){ float g=sgc[hc*64+c]; a+=g*att_src[hc*64+c]; d+=g*att_dst[hc*64+c]; }
      gwbuf[524+hc]=a; gwbuf[526+hc]=d; }
    __syncthreads();
    if (hc < 64){
      int o = hc;
      short* gw2 = wp + 46080;
      float sbias[3];
      for (int dt=0; dt<3; ++dt){
        float s[6] = {0,0,0,0,0,0};
        float sb = 0.f;
        for (int c=0;c<64;++c){
          float wv = tc_w[o*192 + c*3 + dt];
          for (int j=0;j<3;++j){
            s[j]   += wv * sgw[j*128 + c];
            s[3+j] += wv * sgw[j*128 + 64 + c];
          }
          sb += wv * (gat_b[c] + 0.5f*(sgc[c] + sgc[64+c]));
        }
        for (int j=0;j<6;++j) gw2[o*40 + dt*6 + j] = bf(s[j]);
        sbias[dt] = sb;
      }
      for (int k=18;k<40;++k) gw2[o*40+k] = 0;
      for (int t=0;t<16;++t){
        float b = tc_b[o];
        if (t < 12){
          if (t > 0)  b += sbias[0];
          b += sbias[1];
          if (t < 11) b += sbias[2];
        }
        btcT[o*16+t] = b;   // transposed: [o][t] so consumer does float4 over t
      }
    }
    return;
  }
  int i = (blockIdx.x-626)*256 + threadIdx.x;
  if (i >= 46080) return;
  float v;
  if (i < 13824){ int j=i/72, k=i%72; v = (k<64)? in_w[j*64+k] : 0.f; }
  else if (i < 27648){ int d=i-13824; int dt=d/4608, rr=d%4608, o=rr/72, c=rr%72; v = (c<64)? bc_w[o*192+c*3+dt] : 0.f; }
  else if (i < 41472){ int d=i-27648; int dt=d/4608, rr=d%4608, o=rr/72, c=rr%72; v = (c<64)? fc_w[o*192+c*3+dt] : 0.f; }
  else               { int d=i-41472; int o=d/72, c=d%72; v = (c<64)? out_w[o*64+c] : 0.f; }
  wp[i] = bf(v);
}

// ---------------- scan phase A (blocks<157) + repack (blocks>=157) ----------------
// repack: wp2 frag ids f2: QKV 0..23 (grp*8+nt*2+kc) | OUT 24..31 | BC 32..55 | FC 56..79
__global__ void k_scanA(const int* __restrict__ cnt, int* __restrict__ bsum,
                        const short* __restrict__ wp, short* __restrict__ wp2){
  if (blockIdx.x >= 157){
    int i = (blockIdx.x-157)*256 + threadIdx.x;
    if (i >= 40960) return;
    int f2 = i >> 9, lane = (i >> 3) & 63, e = i & 7;
    int l15 = lane & 15, l4 = lane >> 4;
    int src;
    if (f2 < 24){
      int grp = f2 >> 3, nt = (f2 >> 1) & 3, kc = f2 & 1;
      src = 0     + ((grp*4+nt)*16 + l15)*72 + kc*32 + l4*8 + e;
    } else if (f2 < 32){
      int g = f2 - 24; int mt = g >> 1, kc = g & 1;
      src = 41472 + (mt*16 + l15)*72 + kc*32 + l4*8 + e;
    } else if (f2 < 56){
      int g = f2 - 32; int dt = g >> 3, kc = (g >> 2) & 1, nt = g & 3;
      src = 13824 + (dt*64 + nt*16 + l15)*72 + kc*32 + l4*8 + e;
    } else {
      int g = f2 - 56; int dt = g >> 3, kc = (g >> 2) & 1, nt = g & 3;
      src = 27648 + (dt*64 + nt*16 + l15)*72 + kc*32 + l4*8 + e;
    }
    wp2[i] = wp[src];
    return;
  }
  __shared__ int s[256];
  int i = blockIdx.x*256 + threadIdx.x;
  int v = (i < BN) ? cnt[i] : 0;
  s[threadIdx.x] = v; __syncthreads();
  for (int off=128; off>0; off>>=1){
    if (threadIdx.x < off) s[threadIdx.x] += s[threadIdx.x+off];
    __syncthreads();
  }
  if (threadIdx.x == 0) bsum[blockIdx.x] = s[0];
}

__global__ void k_scanB(const int* __restrict__ bsum, int* __restrict__ bbase, int* __restrict__ rowptr){
  __shared__ int s[256];
  int tid = threadIdx.x;
  int v = (tid < 157) ? bsum[tid] : 0;
  s[tid] = v; __syncthreads();
  for (int off=1; off<256; off<<=1){
    int t = (tid>=off) ? s[tid-off] : 0;
    __syncthreads();
    s[tid] += t;
    __syncthreads();
  }
  if (tid < 157) bbase[tid] = s[tid] - v;   // exclusive
  if (tid == 0) rowptr[BN] = EE;
}

__global__ void k_scanC(const int* __restrict__ cnt, const int* __restrict__ bbase,
                        int* __restrict__ rowptr, int* __restrict__ cursor){
  __shared__ int s[256];
  int i = blockIdx.x*256 + threadIdx.x;
  int v = (i < BN) ? cnt[i] : 0;
  s[threadIdx.x] = v; __syncthreads();
  for (int off=1; off<256; off<<=1){
    int t = (threadIdx.x>=off) ? s[threadIdx.x-off] : 0;
    __syncthreads();
    s[threadIdx.x] += t;
    __syncthreads();
  }
  if (i < BN){
    int r = bbase[blockIdx.x] + s[threadIdx.x] - v;
    rowptr[i] = r; cursor[i] = r;
  }
}

__global__ void k_scatter(const int* __restrict__ ei, const int* __restrict__ degcnt,
                          int* __restrict__ cursor, int* __restrict__ esrc, float* __restrict__ ew){
  int e = blockIdx.x*256 + threadIdx.x;
  if (e < EE){
    int s = ei[e], d = ei[EE+e];
    int p = atomicAdd(&cursor[d], 1);
    esrc[p] = s;
    int ds_ = degcnt[s], dd_ = degcnt[d];
    float isd = ds_ > 0 ? rsqrtf((float)ds_) : 0.f;
    float idd = dd_ > 0 ? rsqrtf((float)dd_) : 0.f;
    ew[p] = -isd*idd;
  }
}

// ---------------- Cheb propagation ----------------
__global__ void k_prop1v(const float* __restrict__ x, const int* __restrict__ rowptr,
                         const int* __restrict__ esrc, const float* __restrict__ ew,
                         float* __restrict__ tx1){
  int i = blockIdx.x*256 + threadIdx.x;
  if (i >= BN*3) return;
  int d = i/3, q = i - d*3;
  int r0 = rowptr[d], r1 = rowptr[d+1];
  float4 a = {0.f,0.f,0.f,0.f};
  for (int p=r0;p<r1;++p){
    float wv = ew[p];
    float4 v = ((const float4*)x)[esrc[p]*3 + q];
    a.x += wv*v.x; a.y += wv*v.y; a.z += wv*v.z; a.w += wv*v.w;
  }
  ((float4*)tx1)[i] = a;
}

__global__ void k_prop2v(const float* __restrict__ x, const float* __restrict__ tx1,
                         const int* __restrict__ rowptr, const int* __restrict__ esrc,
                         const float* __restrict__ ew, float* __restrict__ tx2){
  int i = blockIdx.x*256 + threadIdx.x;
  if (i >= BN*3) return;
  int d = i/3, q = i - d*3;
  int r0 = rowptr[d], r1 = rowptr[d+1];
  float4 a = {0.f,0.f,0.f,0.f};
  for (int p=r0;p<r1;++p){
    float wv = ew[p];
    float4 v = ((const float4*)tx1)[esrc[p]*3 + q];
    a.x += wv*v.x; a.y += wv*v.y; a.z += wv*v.z; a.w += wv*v.w;
  }
  float4 xv = ((const float4*)x)[i];
  float4 o; o.x = 2.f*a.x - xv.x; o.y = 2.f*a.y - xv.y; o.z = 2.f*a.z - xv.z; o.w = 2.f*a.w - xv.w;
  ((float4*)tx2)[i] = o;
}

// ---------------- GAT: thread = (node, t-quarter), BOTH heads ----------------
__global__ __launch_bounds__(256) void k_gat4(const float* __restrict__ x, const float* __restrict__ tx1,
     const float* __restrict__ tx2, const int* __restrict__ rowptr, const int* __restrict__ esrc,
     const float* __restrict__ gwbuf, float* __restrict__ coef, int cst){
  int i = blockIdx.x*256 + threadIdx.x;
  if (i >= BN*3) return;
  int d = i/3, q = i - d*3;

  float as[2][3], ad[2][3], asc[2], adc[2];
  #pragma unroll
  for (int h=0;h<2;++h){
    #pragma unroll
    for (int k=0;k<3;++k){ as[h][k] = gwbuf[512+2*k+h]; ad[h][k] = gwbuf[518+2*k+h]; }
    asc[h] = gwbuf[524+h]; adc[h] = gwbuf[526+h];
  }

  float4 t0 = ((const float4*)x)[d*3+q];
  float4 t1 = ((const float4*)tx1)[d*3+q];
  float4 t2 = ((const float4*)tx2)[d*3+q];
  float td0[4] = {t0.x,t0.y,t0.z,t0.w};
  float td1[4] = {t1.x,t1.y,t1.z,t1.w};
  float td2[4] = {t2.x,t2.y,t2.z,t2.w};

  float adh[2][4], S0[2][4], S1[2][4], S2[2][4], Z[2][4];
  #pragma unroll
  for (int h=0;h<2;++h){
    #pragma unroll
    for (int t=0;t<4;++t){
      adh[h][t] = td0[t]*ad[h][0] + td1[t]*ad[h][1] + td2[t]*ad[h][2] + adc[h];
      float es = lrelu(td0[t]*as[h][0] + td1[t]*as[h][1] + td2[t]*as[h][2] + asc[h] + adh[h][t]);
      float p = __expf(es);
      S0[h][t] = p*td0[t]; S1[h][t] = p*td1[t]; S2[h][t] = p*td2[t]; Z[h][t] = p;
    }
  }
  int r0 = rowptr[d], r1 = rowptr[d+1];
  for (int p=r0;p<r1;++p){
    int s = esrc[p];
    float4 v0 = ((const float4*)x)[s*3+q];
    float4 v1 = ((const float4*)tx1)[s*3+q];
    float4 v2 = ((const float4*)tx2)[s*3+q];
    float s0[4] = {v0.x,v0.y,v0.z,v0.w};
    float s1[4] = {v1.x,v1.y,v1.z,v1.w};
    float s2[4] = {v2.x,v2.y,v2.z,v2.w};
    #pragma unroll
    for (int h=0;h<2;++h){
      #pragma unroll
      for (int t=0;t<4;++t){
        float e = lrelu(s0[t]*as[h][0] + s1[t]*as[h][1] + s2[t]*as[h][2] + asc[h] + adh[h][t]);
        float pp = __expf(e);
        S0[h][t] += pp*s0[t]; S1[h][t] += pp*s1[t]; S2[h][t] += pp*s2[t]; Z[h][t] += pp;
      }
    }
  }
  float* cw = coef + (size_t)d*cst + q*32;
  #pragma unroll
  for (int t=0;t<4;++t){
    float inv0 = 0.5f/Z[0][t], inv1 = 0.5f/Z[1][t];
    float4 w4; w4.x = S0[0][t]*inv0; w4.y = S1[0][t]*inv0; w4.z = S2[0][t]*inv0; w4.w = S0[1][t]*inv1;
    *(float4*)(cw + t*8) = w4;
    float2 w2; w2.x = S1[1][t]*inv1; w2.y = S2[1][t]*inv1;
    *(float2*)(cw + t*8 + 4) = w2;
  }
}

// ---------------- fused temporal: 7 nodes / 448-thread block, 53.8 KB LDS, NO barrier ----------------
// per node (3840 shorts): +0 tcO->Q->O [16][72] | +1152 K[16][72] -> R[18][72]
//   +2304 Vt[64][16] | +3328 Pb[16][16] | +3584 Pb2[16][16]
// P3 processes heads in PAIRS (dual P buffers) for ILP
__global__ __launch_bounds__(448) void k_temporal9(
  const float* __restrict__ coef, int cst, const float* __restrict__ x,
  const short* __restrict__ wp, const short* __restrict__ wp2, const float* __restrict__ btcT,
  const float* __restrict__ in_b, const float* __restrict__ out_b,
  const float* __restrict__ res_w, const float* __restrict__ res_b,
  const float* __restrict__ ln_g, const float* __restrict__ ln_b,
  const float* __restrict__ bc_b, const float* __restrict__ fc_b,
  float* __restrict__ out)
{
  __shared__ __align__(16) short lds[26880];   // 7 * 3840 = 53.8 KiB

  const int tid = threadIdx.x;
  const int wv = tid >> 6;
  const int lane = tid & 63;
  const int l15 = lane & 15, l4 = lane >> 4;
  const int nd = blockIdx.x*7 + wv;
  if (nd >= BN) return;

  short* nb  = lds + wv*3840;
  short* tcO = nb;            // tc out -> Q -> O
  short* K   = nb + 1152;
  short* R   = nb + 1152;     // [18][72] over K + head of Vt (both dead after P3)
  short* Vt  = nb + 2304;     // [64][16]
  short* Pb  = nb + 3328;     // [16][16]
  short* Pb2 = nb + 3584;     // [16][16]

  const f32x4 z4 = {0.f,0.f,0.f,0.f};
  s16x8 zf;
  #pragma unroll
  for (int j=0;j<8;++j) zf[j]=0;

  // ---- A-fragment in registers: A[t=l15][k=l4*8+e], k=dt*6+j, zeros k>=18
  s16x8 aA;
  {
    const float* cb = coef + (size_t)nd*cst;
    float av[8];
    #pragma unroll
    for (int e=0; e<8; ++e){
      int k = l4*8 + e;
      float v = 0.f;
      if (k < 18){
        int dt = (k>=12) ? 2 : ((k>=6) ? 1 : 0);
        int j = k - dt*6;
        int u = l15 - 1 + dt;
        if (u >= 0 && u < 12) v = cb[u*8 + j];
      }
      av[e] = v;
    }
    unsigned* ap = (unsigned*)&aA;
    ap[0]=cvtpk(av[0],av[1]); ap[1]=cvtpk(av[2],av[3]);
    ap[2]=cvtpk(av[4],av[5]); ap[3]=cvtpk(av[6],av[7]);
  }

  // ---- P1: tc GEMM (A = coef regs, B = gwtc global row-major) -> tcO[t][o]
  {
    #pragma unroll
    for (int nt=0; nt<4; ++nt){
      s16x8 b = *(const s16x8*)&wp[46080 + (nt*16+l15)*40 + l4*8];
      f32x4 acc = __builtin_amdgcn_mfma_f32_16x16x32_bf16(aA, b, z4, 0,0,0);  // row=t, col=o
      float4 bb = *(const float4*)&btcT[(nt*16+l15)*16 + l4*4];
      unsigned p01 = cvtpk(acc[0]+bb.x, acc[1]+bb.y);
      unsigned p23 = cvtpk(acc[2]+bb.z, acc[3]+bb.w);
      int c = nt*16 + l15, rb = l4*4;
      tcO[(rb+0)*72+c] = (short)p01; tcO[(rb+1)*72+c] = (short)(p01>>16);
      tcO[(rb+2)*72+c] = (short)p23; tcO[(rb+3)*72+c] = (short)(p23>>16);
    }
  }

  // ---- P2: QKV GEMM (B-frags from global wp2) -> Q(=tcO region), K, Vt
  {
    s16x8 a0 = *(const s16x8*)&tcO[l15*72 +  0 + l4*8];
    s16x8 a1 = *(const s16x8*)&tcO[l15*72 + 32 + l4*8];
    #pragma unroll
    for (int grp=0; grp<3; ++grp){
      f32x4 acc[4];
      #pragma unroll
      for (int nt=0; nt<4; ++nt){
        s16x8 b0 = *(const s16x8*)&wp2[(((grp*8 + nt*2 + 0)*64 + lane))*8];
        acc[nt] = __builtin_amdgcn_mfma_f32_16x16x32_bf16(a0, b0, z4, 0,0,0);
        s16x8 b1 = *(const s16x8*)&wp2[(((grp*8 + nt*2 + 1)*64 + lane))*8];
        acc[nt] = __builtin_amdgcn_mfma_f32_16x16x32_bf16(a1, b1, acc[nt], 0,0,0);
      }
      #pragma unroll
      for (int nt=0; nt<4; ++nt){
        float bb = in_b[(grp*4+nt)*16 + l15];
        unsigned p01 = cvtpk(acc[nt][0]+bb, acc[nt][1]+bb);
        unsigned p23 = cvtpk(acc[nt][2]+bb, acc[nt][3]+bb);
        if (grp==0){
          int c = nt*16+l15, rb = l4*4;
          tcO[(rb+0)*72+c] = (short)p01; tcO[(rb+1)*72+c] = (short)(p01>>16);
          tcO[(rb+2)*72+c] = (short)p23; tcO[(rb+3)*72+c] = (short)(p23>>16);
        } else if (grp==1){
          int c = nt*16+l15, rb = l4*4;
          K[(rb+0)*72+c] = (short)p01; K[(rb+1)*72+c] = (short)(p01>>16);
          K[(rb+2)*72+c] = (short)p23; K[(rb+3)*72+c] = (short)(p23>>16);
        } else {
          int2 pk2; pk2.x = (int)p01; pk2.y = (int)p23;
          *(int2*)&Vt[(nt*16 + l15)*16 + l4*4] = pk2;
        }
      }
    }
  }

  // ---- P3: attention, heads in PAIRS (dual P buffers -> two independent chains in flight)
  {
    #pragma unroll 1
    for (int hp=0; hp<2; ++hp){
      const int h0 = hp*2, h1 = hp*2 + 1;
      s16x8 qa0 = zf, kb0 = zf, qa1 = zf, kb1 = zf;
      if (l4 < 2){
        qa0 = *(const s16x8*)&tcO[l15*72 + h0*16 + l4*8];   // Q h0
        kb0 = *(const s16x8*)&K[l15*72 + h0*16 + l4*8];
        qa1 = *(const s16x8*)&tcO[l15*72 + h1*16 + l4*8];   // Q h1
        kb1 = *(const s16x8*)&K[l15*72 + h1*16 + l4*8];
      }
      f32x4 sc0 = __builtin_amdgcn_mfma_f32_16x16x32_bf16(qa0, kb0, z4, 0,0,0);  // row=q, col=kt
      f32x4 sc1 = __builtin_amdgcn_mfma_f32_16x16x32_bf16(qa1, kb1, z4, 0,0,0);
      float invz0[4], invz1[4], ev0[4], ev1[4];
      #pragma unroll
      for (int r=0; r<4; ++r){
        float e0 = (l15 < 12) ? __expf(sc0[r]*0.25f) : 0.f;
        float e1 = (l15 < 12) ? __expf(sc1[r]*0.25f) : 0.f;
        float z0 = e0, z1 = e1;
        #pragma unroll
        for (int dd=1; dd<16; dd<<=1){ z0 += __shfl_xor(z0, dd); z1 += __shfl_xor(z1, dd); }
        invz0[r] = 1.f/z0; invz1[r] = 1.f/z1;
        ev0[r] = e0; ev1[r] = e1;
      }
      {
        unsigned a01 = cvtpk(ev0[0],ev0[1]), a23 = cvtpk(ev0[2],ev0[3]);
        unsigned b01 = cvtpk(ev1[0],ev1[1]), b23 = cvtpk(ev1[2],ev1[3]);
        int rb = l4*4, c = l15;
        Pb [(rb+0)*16+c] = (short)a01; Pb [(rb+1)*16+c] = (short)(a01>>16);
        Pb [(rb+2)*16+c] = (short)a23; Pb [(rb+3)*16+c] = (short)(a23>>16);
        Pb2[(rb+0)*16+c] = (short)b01; Pb2[(rb+1)*16+c] = (short)(b01>>16);
        Pb2[(rb+2)*16+c] = (short)b23; Pb2[(rb+3)*16+c] = (short)(b23>>16);
      }
      s16x8 pa0 = zf, vb0 = zf, pa1 = zf, vb1 = zf;
      if (l4 < 2){
        pa0 = *(const s16x8*)&Pb [l15*16 + l4*8];
        vb0 = *(const s16x8*)&Vt[(h0*16 + l15)*16 + l4*8];
        pa1 = *(const s16x8*)&Pb2[l15*16 + l4*8];
        vb1 = *(const s16x8*)&Vt[(h1*16 + l15)*16 + l4*8];
      }
      f32x4 ov0 = __builtin_amdgcn_mfma_f32_16x16x32_bf16(pa0, vb0, z4, 0,0,0);  // row=q, col=dh
      f32x4 ov1 = __builtin_amdgcn_mfma_f32_16x16x32_bf16(pa1, vb1, z4, 0,0,0);
      {
        unsigned a01 = cvtpk(ov0[0]*invz0[0], ov0[1]*invz0[1]);
        unsigned a23 = cvtpk(ov0[2]*invz0[2], ov0[3]*invz0[3]);
        unsigned b01 = cvtpk(ov1[0]*invz1[0], ov1[1]*invz1[1]);
        unsigned b23 = cvtpk(ov1[2]*invz1[2], ov1[3]*invz1[3]);
        int c0 = h0*16 + l15, c1 = h1*16 + l15, rb = l4*4;
        tcO[(rb+0)*72+c0] = (short)a01; tcO[(rb+1)*72+c0] = (short)(a01>>16);
        tcO[(rb+2)*72+c0] = (short)a23; tcO[(rb+3)*72+c0] = (short)(a23>>16);
        tcO[(rb+0)*72+c1] = (short)b01; tcO[(rb+1)*72+c1] = (short)(b01>>16);
        tcO[(rb+2)*72+c1] = (short)b23; tcO[(rb+3)*72+c1] = (short)(b23>>16);
      }
    }
  }

  // ---- P4: out-proj (frags from global wp2) + residual + relu + LN -> R[u][o]
  {
    s16x4 zz; zz[0]=0; zz[1]=0; zz[2]=0; zz[3]=0;
    for (int i=lane; i<108; i+=64){
      int rr = i/18, cc = i%18;
      int row = (rr==0) ? 0 : (12 + rr);
      *(s16x4*)&R[row*72 + cc*4] = zz;
    }
    s16x8 a0 = *(const s16x8*)&tcO[l15*72 +  0 + l4*8];
    s16x8 a1 = *(const s16x8*)&tcO[l15*72 + 32 + l4*8];
    f32x4 acc[4];
    #pragma unroll
    for (int nt=0; nt<4; ++nt){
      s16x8 w0 = *(const s16x8*)&wp2[(((24 + nt*2 + 0)*64 + lane))*8];
      acc[nt] = __builtin_amdgcn_mfma_f32_16x16x32_bf16(a0, w0, z4, 0,0,0);
      s16x8 w1 = *(const s16x8*)&wp2[(((24 + nt*2 + 1)*64 + lane))*8];
      acc[nt] = __builtin_amdgcn_mfma_f32_16x16x32_bf16(a1, w1, acc[nt], 0,0,0); // row=t, col=o
    }
    float4 xv = {0.f,0.f,0.f,0.f};
    if (l4 < 3) xv = *(const float4*)&x[(size_t)nd*12 + l4*4];
    float xr[4] = {xv.x, xv.y, xv.z, xv.w};
    float zr[4][4], sum[4]={0,0,0,0}, sq[4]={0,0,0,0};
    #pragma unroll
    for (int nt=0; nt<4; ++nt){
      int o = nt*16 + l15;
      float ob=out_b[o], rw=res_w[o], rb2=res_b[o];
      #pragma unroll
      for (int r=0; r<4; ++r){
        float v = acc[nt][r] + ob + xr[r]*rw + rb2;
        v = v>0.f ? v : 0.f;
        zr[nt][r]=v; sum[r]+=v; sq[r]+=v*v;
      }
    }
    #pragma unroll
    for (int r=0; r<4; ++r){
      #pragma unroll
      for (int dd=1; dd<16; dd<<=1){ sum[r]+=__shfl_xor(sum[r],dd); sq[r]+=__shfl_xor(sq[r],dd); }
    }
    if (l4 < 3){
      float mu4[4], iv4[4];
      #pragma unroll
      for (int r=0; r<4; ++r){
        float mu = sum[r]*(1.f/64.f);
        float va = sq[r]*(1.f/64.f) - mu*mu;
        mu4[r] = mu; iv4[r] = rsqrtf(fmaxf(va,0.f) + 1e-5f);
      }
      #pragma unroll
      for (int nt=0; nt<4; ++nt){
        int o = nt*16 + l15;
        float g = ln_g[o], b2 = ln_b[o];
        float r0 = (zr[nt][0]-mu4[0])*iv4[0]*g + b2;
        float r1 = (zr[nt][1]-mu4[1])*iv4[1]*g + b2;
        float r2 = (zr[nt][2]-mu4[2])*iv4[2]*g + b2;
        float r3 = (zr[nt][3]-mu4[3])*iv4[3]*g + b2;
        unsigned p01 = cvtpk(r0,r1), p23 = cvtpk(r2,r3);
        int rb = l4*4;
        R[(rb+1)*72+o] = (short)p01; R[(rb+2)*72+o] = (short)(p01>>16);
        R[(rb+3)*72+o] = (short)p23; R[(rb+4)*72+o] = (short)(p23>>16);
      }
    }
  }

  // ---- P5+P6 fused: backcast+forecast convs (A = R rows, B = global wp2 frags)
  {
    f32x4 aB[4] = {z4,z4,z4,z4};
    f32x4 aF[4] = {z4,z4,z4,z4};
    #pragma unroll
    for (int dt=0; dt<3; ++dt){
      #pragma unroll
      for (int kc=0; kc<2; ++kc){
        s16x8 ar = *(const s16x8*)&R[(l15 + dt)*72 + kc*32 + l4*8];
        #pragma unroll
        for (int nt=0; nt<4; ++nt){
          s16x8 wb = *(const s16x8*)&wp2[16384 + (((dt*8 + kc*4 + nt)*64 + lane))*8];
          aB[nt] = __builtin_amdgcn_mfma_f32_16x16x32_bf16(ar, wb, aB[nt], 0,0,0);
          s16x8 wf = *(const s16x8*)&wp2[28672 + (((dt*8 + kc*4 + nt)*64 + lane))*8];
          aF[nt] = __builtin_amdgcn_mfma_f32_16x16x32_bf16(ar, wf, aF[nt], 0,0,0);
        }
      }
    }
    if (l4 < 3){
      #pragma unroll
      for (int nt=0; nt<4; ++nt){
        int o = nt*16 + l15;
        float bb = bc_b[o], fb = fc_b[o];
        float4 v; v.x=aB[nt][0]+bb; v.y=aB[nt][1]+bb; v.z=aB[nt][2]+bb; v.w=aB[nt][3]+bb;
        *(float4*)&out[(size_t)nd*768 + o*12 + l4*4] = v;
        float4 f; f.x=aF[nt][0]+fb; f.y=aF[nt][1]+fb; f.z=aF[nt][2]+fb; f.w=aF[nt][3]+fb;
        *(float4*)&out[30720000 + (size_t)nd*768 + o*12 + l4*4] = f;
      }
    }
  }
}

// ---------------- host ----------------
extern "C" void kernel_launch(void* const* d_in, const int* in_sizes, int n_in,
                              void* d_out, int out_size, void* d_ws, size_t ws_size,
                              hipStream_t stream){
  const float* x      = (const float*)d_in[0];
  const int*   ei     = (const int*)d_in[1];
  const float* cheb_w = (const float*)d_in[2];
  const float* cheb_b = (const float*)d_in[3];
  const float* gat_w  = (const float*)d_in[4];
  const float* att_src= (const float*)d_in[5];
  const float* att_dst= (const float*)d_in[6];
  const float* gat_b  = (const float*)d_in[7];
  const float* tc_w   = (const float*)d_in[8];
  const float* tc_b   = (const float*)d_in[9];
  const float* in_w   = (const float*)d_in[10];
  const float* in_b   = (const float*)d_in[11];
  const float* out_w  = (const float*)d_in[12];
  const float* out_b  = (const float*)d_in[13];
  const float* res_w  = (const float*)d_in[14];
  const float* res_b  = (const float*)d_in[15];
  const float* ln_g   = (const float*)d_in[16];
  const float* ln_b   = (const float*)d_in[17];
  const float* bc_w   = (const float*)d_in[18];
  const float* bc_b   = (const float*)d_in[19];
  const float* fc_w   = (const float*)d_in[20];
  const float* fc_b   = (const float*)d_in[21];
  float* out = (float*)d_out;

  char* w = (char*)d_ws;
  size_t off = 0;
  auto alloc = [&](size_t bytes)->void*{ void* p = w + off; off += (bytes + 255) & ~(size_t)255; return p; };
  int*   cnt2   = (int*)alloc((size_t)2*BN*4);
  int*   degcnt = cnt2;
  int*   cnt    = cnt2 + BN;
  int*   rowptr = (int*)alloc((size_t)(BN+1)*4);
  int*   cursor = (int*)alloc((size_t)BN*4);
  int*   esrc   = (int*)alloc((size_t)EE*4);
  float* ew     = (float*)alloc((size_t)EE*4);
  float* tx1    = (float*)alloc((size_t)BN*TT*4);
  float* tx2    = (float*)alloc((size_t)BN*TT*4);
  float* gwb    = (float*)alloc(1024*4);
  short* wpack  = (short*)alloc((size_t)48640*2);
  short* wpack2 = (short*)alloc((size_t)40960*2);
  float* btcT   = (float*)alloc(1024*4);
  int*   bsum   = (int*)alloc(157*4);
  int*   bbase  = (int*)alloc(157*4);

  size_t coefBytes = (size_t)BN*TT*8*4;
  float* coefp; int cst;
  if (off + coefBytes <= ws_size){ coefp = (float*)(w + off); off += coefBytes; cst = 96; }
  else { coefp = out; cst = 768; }

  hipMemsetAsync(cnt2, 0, (size_t)2*BN*4, stream);
  k_histprep<<<806, 256, 0, stream>>>(ei, degcnt, cnt, cheb_w, cheb_b, gat_w, att_src, att_dst,
                                      gat_b, tc_w, tc_b, in_w, out_w, bc_w, fc_w, gwb, wpack, btcT);
  k_scanA   <<<317, 256, 0, stream>>>(cnt, bsum, wpack, wpack2);
  k_scanB   <<<1, 256, 0, stream>>>(bsum, bbase, rowptr);
  k_scanC   <<<157, 256, 0, stream>>>(cnt, bbase, rowptr, cursor);
  k_scatter <<<(EE+255)/256, 256, 0, stream>>>(ei, degcnt, cursor, esrc, ew);
  k_prop1v  <<<(BN*3+255)/256, 256, 0, stream>>>(x, rowptr, esrc, ew, tx1);
  k_prop2v  <<<(BN*3+255)/256, 256, 0, stream>>>(x, tx1, rowptr, esrc, ew, tx2);
  k_gat4    <<<(BN*3+255)/256, 256, 0, stream>>>(x, tx1, tx2, rowptr, esrc, gwb, coefp, cst);
  k_temporal9<<<(BN+6)/7, 448, 0, stream>>>(coefp, cst, x, wpack, wpack2, btcT, in_b, out_b,
                                            res_w, res_b, ln_g, ln_b, bc_b, fc_b, out);
}